// Round 5
// baseline (469.902 us; speedup 1.0000x reference)
//
#include <hip/hip_runtime.h>

#define MEM_SIZE 1000000
#define DIM 128
#define BS 256
#define K 1024
#define NSC (K + 1)   // 1025 scores per (modality, batch)

constexpr float INV_TEMP = 1.0f / 0.07f;
constexpr float MOM = 0.5f;

#define NB 2048                       // blocks
#define BT 256                        // threads per block (4 waves)
#define S  ((long long)NB * BT)       // 524288 fx4 grid stride
#define MARGIN_ROWS 32768             // trail the copy frontier by ~1 iteration

typedef float fx4 __attribute__((ext_vector_type(4)));

__device__ __forceinline__ float wave_reduce_sum(float v) {
    #pragma unroll
    for (int off = 32; off > 0; off >>= 1)
        v += __shfl_xor(v, off, 64);
    return v;
}

// Processes all not-yet-done entries whose row < rmax. key = (row<<11)|j.
// Wave-cooperative: each ready entry's 512B row is gathered by all 64 lanes
// (float2 per lane), reduced, and lane==src writes the score.
__device__ __forceinline__ void drain(unsigned key, bool& done, int rmax,
                                      const float2* __restrict__ gmem,
                                      float qx, float qy,
                                      float* __restrict__ srow, int lane) {
    const bool rdy = !done && (int)(key >> 11) < rmax;
    unsigned long long msk = __ballot(rdy);
    while (msk) {
        const int src = __ffsll((long long)msk) - 1;
        msk &= msk - 1;
        const unsigned k = (unsigned)__shfl((int)key, src, 64);
        const int row = (int)(k >> 11);
        const int j = (int)(k & 2047u);
        const float2 x = gmem[(size_t)row * 64 + lane];
        const float sc = wave_reduce_sum(x.x * qx + x.y * qy);
        if (lane == src) srow[j] = sc * INV_TEMP;
    }
    done = done || rdy;
}

// Homogeneous fused kernel: every block copies its stride-slice of both banks
// (2x unrolled) AND owns one slice of scores for one (m,b) unit — exactly one
// negative entry per lane — draining gathers just behind its own copy frontier
// so they hit L3 (the copy just streamed those rows).
__global__ __launch_bounds__(BT, 8) void fused_kernel(
    const float* __restrict__ video, const float* __restrict__ audio,
    const int* __restrict__ y, const int* __restrict__ neg,
    const float* __restrict__ view1, const float* __restrict__ view2,
    float* __restrict__ scores,
    fx4* __restrict__ out1, fx4* __restrict__ out2) {
    const int bid = blockIdx.x;
    const int tid = threadIdx.x;
    const int lane = tid & 63;
    const int wv = tid >> 6;            // wave 0..3
    const int u = bid >> 2;             // score unit 0..511
    const int s = bid & 3;              // slice 0..3
    const int m = u >> 8;               // 0: view2·v, 1: view1·a
    const int b = u & (BS - 1);
    const int yb = y[b];

    // block-uniform normalized query (held in 2 VGPRs)
    const float* emb = (m == 0) ? video : audio;
    const float2 e = reinterpret_cast<const float2*>(emb + b * DIM)[lane];
    const float ss = wave_reduce_sum(e.x * e.x + e.y * e.y);
    const float qinv = 1.0f / fmaxf(sqrtf(ss), 1e-12f);
    const float qx = e.x * qinv, qy = e.y * qinv;

    // this lane's single negative-score entry
    const int j0 = 1 + s * 256 + wv * 64 + lane;      // 1..1024
    const int ni0 = neg[b * K + j0 - 1];
    const int r0 = ni0 + (ni0 >= yb ? 1 : 0);
    const unsigned key0 = ((unsigned)r0 << 11) | (unsigned)j0;
    bool done0 = false;

    const float2* gmem =
        reinterpret_cast<const float2*>((m == 0) ? view2 : view1);
    float* srow = scores + (size_t)u * NSC;

    const fx4* s1 = reinterpret_cast<const fx4*>(view1);
    const fx4* s2 = reinterpret_cast<const fx4*>(view2);

    const long long n4 = (long long)MEM_SIZE * DIM / 4;   // 32,000,000 fx4
    long long i = (long long)bid * BT + tid;
    long long ibase = (long long)bid * BT;                // block frontier proxy
    for (; i < n4; i += 2 * S, ibase += 2 * S) {
        // copy, 2x unrolled (4 loads in flight); normal loads populate L3,
        // nontemporal stores avoid polluting it.
        const long long i1 = i + S;
        const bool g = i1 < n4;
        const fx4 a0 = s1[i];
        const fx4 c0 = s2[i];
        fx4 a1, c1;
        if (g) { a1 = s1[i1]; c1 = s2[i1]; }
        __builtin_nontemporal_store(a0, &out1[i]);
        __builtin_nontemporal_store(c0, &out2[i]);
        if (g) {
            __builtin_nontemporal_store(a1, &out1[i1]);
            __builtin_nontemporal_store(c1, &out2[i1]);
        }
        // drain score entries well behind the frontier (L3-resident rows)
        const int rmax = (int)(ibase >> 5) - MARGIN_ROWS;
        drain(key0, done0, rmax, gmem, qx, qy, srow, lane);
    }
    // final drain: everything left (rows near the end, just streamed)
    drain(key0, done0, 0x7fffffff, gmem, qx, qy, srow, lane);

    // positive score (j=0): one wave per unit
    if (s == 0 && wv == 0) {
        const float2 x = gmem[(size_t)yb * 64 + lane];
        const float sc = wave_reduce_sum(x.x * qx + x.y * qy);
        if (lane == 0) srow[0] = sc * INV_TEMP;
    }
}

// Overwrite the 256 momentum-updated rows per bank (after the copy).
// Duplicate y: numpy "last wins" -> skip b if a later b' has the same index.
__global__ void scatter_kernel(const float* __restrict__ video,
                               const float* __restrict__ audio,
                               const int* __restrict__ y,
                               const float* __restrict__ view1,
                               const float* __restrict__ view2,
                               float* __restrict__ out1,
                               float* __restrict__ out2) {
    const int blk = blockIdx.x;
    const int lane = threadIdx.x;
    const int bank = blk >> 8;
    const int b = blk & (BS - 1);
    const int row = y[b];
    for (int b2 = b + 1; b2 < BS; ++b2)
        if (y[b2] == row) return;   // a later write supersedes this one

    const float* emb = (bank == 0) ? video : audio;
    const float2 e = reinterpret_cast<const float2*>(emb + b * DIM)[lane];
    const float ss = wave_reduce_sum(e.x * e.x + e.y * e.y);
    const float inv = 1.0f / fmaxf(sqrtf(ss), 1e-12f);
    const float vx = e.x * inv, vy = e.y * inv;

    const float* mem = (bank == 0) ? view1 : view2;
    const float2 xp =
        reinterpret_cast<const float2*>(mem + (size_t)row * DIM)[lane];
    float2 nv = make_float2(MOM * xp.x + (1.0f - MOM) * vx,
                            MOM * xp.y + (1.0f - MOM) * vy);
    const float ss2 = wave_reduce_sum(nv.x * nv.x + nv.y * nv.y);
    const float inv2 = 1.0f / fmaxf(sqrtf(ss2), 1e-12f);
    float* out = (bank == 0) ? out1 : out2;
    reinterpret_cast<float2*>(out + (size_t)row * DIM)[lane] =
        make_float2(nv.x * inv2, nv.y * inv2);
}

extern "C" void kernel_launch(void* const* d_in, const int* in_sizes, int n_in,
                              void* d_out, int out_size, void* d_ws, size_t ws_size,
                              hipStream_t stream) {
    const float* video = (const float*)d_in[0];
    const float* audio = (const float*)d_in[1];
    const int* y       = (const int*)d_in[2];
    const int* neg     = (const int*)d_in[3];
    const float* v1    = (const float*)d_in[4];
    const float* v2    = (const float*)d_in[5];

    float* out    = (float*)d_out;
    float* scores = out;                                   // [2,256,1025]
    float* out1   = out + 2 * BS * NSC;                    // +524800 (16B-aligned)
    float* out2   = out1 + (size_t)MEM_SIZE * DIM;

    fused_kernel<<<NB, BT, 0, stream>>>(
        video, audio, y, neg, v1, v2,
        scores, (fx4*)out1, (fx4*)out2);

    scatter_kernel<<<2 * BS, 64, 0, stream>>>(video, audio, y, v1, v2,
                                              out1, out2);
}